// Round 6
// baseline (340.176 us; speedup 1.0000x reference)
//
#include <hip/hip_runtime.h>

// RelativeMultiHeadAttention (B=8, T=2048, D_MODEL=1024, H=16, D_HEAD=64)
// Round 6: 128x256 GEMM, BK=32, 3-region rotating LDS (72KB) -> 2 blocks/CU,
// 1 barrier/phase, counted VMC(3), T2 swizzle, T5 setprio, XCD remap.
//
// rel_shift: shifted[m] = pos_score[f=m+8 over flat (b*(T+1)+t)]:
//   b_s = f/2049, t_s = f%2049; zero block if t_s==0 else source (b_s, t_s-1).

typedef __attribute__((ext_vector_type(8))) short short8;
typedef __attribute__((ext_vector_type(4))) float f32x4;

__device__ __forceinline__ ushort f2bf(float f) {
    unsigned u = __float_as_uint(f);
    u += 0x7FFFu + ((u >> 16) & 1u);   // round-to-nearest-even
    return (ushort)(u >> 16);
}
__device__ __forceinline__ float bf2f(ushort u) {
    return __uint_as_float(((unsigned)u) << 16);
}

typedef const unsigned int __attribute__((address_space(1)))* gas_t;
typedef unsigned int __attribute__((address_space(3)))* las_t;
__device__ __forceinline__ void gl_lds16(const ushort* g, ushort* l) {
    // direct global->LDS, 16B per lane; LDS dest = wave-uniform base + lane*16
    __builtin_amdgcn_global_load_lds((gas_t)g, (las_t)l, 16, 0, 0);
}

// ---------------- f32 -> bf16 convert (8 elems/thread) ----------------
__global__ __launch_bounds__(256)
void conv_bf16_k(const float* __restrict__ in, ushort* __restrict__ out)
{
    const size_t i = ((size_t)blockIdx.x * 256 + threadIdx.x) * 8;
    float4 a = *(const float4*)(in + i);
    float4 b = *(const float4*)(in + i + 4);
    short8 o = {(short)f2bf(a.x), (short)f2bf(a.y), (short)f2bf(a.z), (short)f2bf(a.w),
                (short)f2bf(b.x), (short)f2bf(b.y), (short)f2bf(b.z), (short)f2bf(b.w)};
    *(short8*)(out + i) = o;
}

// ---------------- Wt[n][k] = bf16(W[k][n]) ----------------
__global__ __launch_bounds__(256)
void transpose_convert_k(const float* __restrict__ W, ushort* __restrict__ Wt, int K, int N)
{
    __shared__ float tile[32][33];
    const int tx = threadIdx.x & 31;
    const int ty = threadIdx.x >> 5;   // 0..7
    const int n0 = blockIdx.x * 32;
    const int k0 = blockIdx.y * 32;
#pragma unroll
    for (int i = 0; i < 4; ++i)
        tile[ty + i * 8][tx] = W[(size_t)(k0 + ty + i * 8) * N + n0 + tx];
    __syncthreads();
#pragma unroll
    for (int i = 0; i < 4; ++i)
        Wt[(size_t)(n0 + ty + i * 8) * K + k0 + tx] = f2bf(tile[tx][ty + i * 8]);
}

// ---------------- bias concat [bq;bk;bv] ----------------
__global__ __launch_bounds__(256)
void bias_concat_k(const float* __restrict__ b0, const float* __restrict__ b1,
                   const float* __restrict__ b2, float* __restrict__ out)
{
    const int i = blockIdx.x * 256 + threadIdx.x;   // 0..3071
    const int s = i >> 10;
    const int j = i & 1023;
    out[i] = (s == 0) ? b0[j] : (s == 1) ? b1[j] : b2[j];
}

// ======== 128x256 GEMM, BK=32, 3-region LDS: C = A[M][K] @ Bt[N][K]^T ========
// 512 thr = 8 waves (2x4); per-wave C: 64x64 (4x4 frags of 16x16), acc ~64 AGPR.
// LDS: A [3][128][32] = 24KB, B [3][256][32] = 48KB -> 72KB => 2 blocks/CU.
// Swizzle: colbyte ^= ((row>>1)&3)<<4 (staging-source AND ds_read side).
// Phase t (region cur=t%3, stage target stg=(t+2)%3):
//   issue stage(t+2) (3 gl_lds); ds_read A4+B4 (b128); lgkmcnt(0);
//   setprio(1); 16 MFMA; setprio(0); VMC; s_barrier.
// FIFO: end of t outstanding = stage(t+1)+stage(t+2) = 6 -> VMC(3) forces
//   stage(t+1) (needed next phase). Tail: VMC(0)@NT-2, nothing @NT-1.
// Region safety: stg was last read in phase t-1; every wave's reads complete
//   before its phase-(t-1) MFMA (lgkm), hence before the end-of-(t-1) barrier,
//   which precedes this issue -> strictly safe.

#define VMC(n) asm volatile("s_waitcnt vmcnt(" #n ")" ::: "memory")

template<int HAS_BIAS, int OUT_BF16>
__global__ __launch_bounds__(512, 4)
void gemm6_k(const ushort* __restrict__ A, const ushort* __restrict__ Bt,
             const float* __restrict__ bias, void* __restrict__ Cv,
             int N, int K)
{
    __shared__ ushort As[3 * 4096];   // 24KB: [3][128][32]
    __shared__ ushort Bs[3 * 8192];   // 48KB: [3][256][32]
    const int tid = threadIdx.x;
    const int l = tid & 63;
    const int w = tid >> 6;
    const int wr = w >> 2;             // 0..1 (m 64-half)
    const int wc = w & 3;              // 0..3 (n 64-quarter)

    // XCD/L2-aware bijective remap: each XCD owns a y-band (gy/8 rows),
    // traversed in 4x4 block sub-tiles. Requires gx%4==0, gy%8==0.
    const int gx = gridDim.x;
    const int lin = blockIdx.y * gx + blockIdx.x;
    const int xcd = lin & 7;
    const int idx = lin >> 3;
    const int hb = gridDim.y >> 3;     // y-band height (blocks)
    const int sxc = gx >> 2;           // 4-wide x sub-tiles
    const int g4 = idx >> 4;
    const int li = idx & 15;
    const int bx = (g4 % sxc) * 4 + (li & 3);
    const int by = xcd * hb + (g4 / sxc) * 4 + (li >> 2);
    const int bm = by * 128;
    const int bn = bx * 256;
    const int NT = K >> 5;             // K-tiles of 32 (NT>=3)

    // staging lane consts: thread covers LDS slot tid*16B of each region;
    // row = tid>>2, physical colbyte (tid&3)*16, pre-swizzled global col:
    const int srow = tid >> 2;          // 0..127
    const int scol = ((tid & 3) ^ ((tid >> 3) & 3)) * 8;
    const ushort* Ag  = A  + (size_t)(bm + srow) * K + scol;
    const ushort* Bg  = Bt + (size_t)(bn + srow) * K + scol;        // rows 0..127
    const ushort* Bg2 = Bg + (size_t)128 * K;                       // rows 128..255
    const int lw = w * 512;             // wave's lds chunk (ushorts)

    // frag ds_read lane consts: row +lr, swizzled k-off fb
    const int lr = l & 15;
    const int fb = (((l >> 4) ^ ((l >> 1) & 3)) * 8);
    const int laneA = (wr * 64 + lr) * 32 + fb;
    const int laneB = (wc * 64 + lr) * 32 + fb;

    f32x4 acc[4][4];
#pragma unroll
    for (int i = 0; i < 4; ++i)
#pragma unroll
        for (int n = 0; n < 4; ++n)
            acc[i][n] = (f32x4){0.f, 0.f, 0.f, 0.f};

#define STAGE6(tt, rg) do { \
    ushort* ha = As + (rg) * 4096 + lw; \
    ushort* hb = Bs + (rg) * 8192 + lw; \
    const size_t ko = (size_t)(tt) * 32; \
    gl_lds16(Ag + ko, ha); \
    gl_lds16(Bg + ko, hb); \
    gl_lds16(Bg2 + ko, hb + 4096); \
} while (0)

    // prologue: stage t0->r0, t1->r1; VMC(3) lands stage(0); barrier
    STAGE6(0, 0);
    STAGE6(1, 1);
    VMC(3);
    __builtin_amdgcn_s_barrier();
    __builtin_amdgcn_sched_barrier(0);

    int cur = 0, stg = 2;
    for (int t = 0; t < NT; ++t) {
        if (t + 2 < NT) STAGE6(t + 2, stg);
        const ushort* ap = As + cur * 4096 + laneA;
        const ushort* bp = Bs + cur * 8192 + laneB;
        short8 af[4], bf4[4];
#pragma unroll
        for (int m = 0; m < 4; ++m) af[m] = *(const short8*)(ap + m * 512);
#pragma unroll
        for (int n = 0; n < 4; ++n) bf4[n] = *(const short8*)(bp + n * 512);
        asm volatile("s_waitcnt lgkmcnt(0)" ::: "memory");
        __builtin_amdgcn_sched_barrier(0);
        __builtin_amdgcn_s_setprio(1);
#pragma unroll
        for (int m = 0; m < 4; ++m)
#pragma unroll
            for (int n = 0; n < 4; ++n)
                acc[m][n] = __builtin_amdgcn_mfma_f32_16x16x32_bf16(af[m], bf4[n], acc[m][n], 0, 0, 0);
        __builtin_amdgcn_s_setprio(0);
        __builtin_amdgcn_sched_barrier(0);
        if (t < NT - 2) { VMC(3); }
        else if (t == NT - 2) { VMC(0); }
        if (t < NT - 1) {
            __builtin_amdgcn_s_barrier();
            __builtin_amdgcn_sched_barrier(0);
        }
        cur = (cur == 2) ? 0 : cur + 1;
        stg = (stg == 2) ? 0 : stg + 1;
    }
#undef STAGE6

    // epilogue: C/D layout col=lane&15, row=(lane>>4)*4+reg
    const int cr = (l >> 4) * 4;
    const int cc = l & 15;
    float bv[4];
#pragma unroll
    for (int n = 0; n < 4; ++n)
        bv[n] = HAS_BIAS ? bias[bn + wc * 64 + n * 16 + cc] : 0.f;
#pragma unroll
    for (int m = 0; m < 4; ++m) {
#pragma unroll
        for (int n = 0; n < 4; ++n) {
            const int col = bn + wc * 64 + n * 16 + cc;
#pragma unroll
            for (int r = 0; r < 4; ++r) {
                const int row = bm + wr * 64 + m * 16 + cr + r;
                float v = acc[m][n][r] + bv[n];
                if (OUT_BF16) ((ushort*)Cv)[(size_t)row * N + col] = f2bf(v);
                else          ((float*)Cv)[(size_t)row * N + col] = v;
            }
        }
    }
}

// ---------------- per-(b,t) attention ----------------
// qkv: [16384][3072] (q|k|v per timestep), pbuf: [16384][1024]
__global__ __launch_bounds__(256)
void attn_k(const ushort* __restrict__ qkv, const ushort* __restrict__ pbuf,
            const float* __restrict__ ubias, const float* __restrict__ vbias,
            const int* __restrict__ masks, ushort* __restrict__ ctx)
{
    __shared__ float qu[16][65];   // q(m)+u_bias
    __shared__ float kk[16][65];
    __shared__ float vv[16][65];
    __shared__ float qv[16][65];   // q(mp)+v_bias (rel-shift source)
    __shared__ float pp[16][65];
    __shared__ float at[16][16];

    const int m  = blockIdx.x;         // b2*T + t2
    const int b2 = m >> 11;
    const int t2 = m & 2047;
    const int f  = m + 8;              // rel-shift: flat block index + B
    const int bs = f / 2049;
    const int ts = f - bs * 2049;
    const bool haspos = (ts != 0);     // ts==0 -> zero pad row
    const int mp = bs * 2048 + ts - 1;

    const int tid = threadIdx.x;
    const int e = tid * 4;
    const int h = e >> 6;
    const int d = e & 63;

    {
        const ushort* base = qkv + (size_t)m * 3072;
        ushort4 a = *(const ushort4*)(base + e);
        ushort4 b = *(const ushort4*)(base + 1024 + e);
        ushort4 c = *(const ushort4*)(base + 2048 + e);
        float4 uu = *(const float4*)(ubias + e);
        qu[h][d + 0] = bf2f(a.x) + uu.x;
        qu[h][d + 1] = bf2f(a.y) + uu.y;
        qu[h][d + 2] = bf2f(a.z) + uu.z;
        qu[h][d + 3] = bf2f(a.w) + uu.w;
        kk[h][d + 0] = bf2f(b.x);
        kk[h][d + 1] = bf2f(b.y);
        kk[h][d + 2] = bf2f(b.z);
        kk[h][d + 3] = bf2f(b.w);
        vv[h][d + 0] = bf2f(c.x);
        vv[h][d + 1] = bf2f(c.y);
        vv[h][d + 2] = bf2f(c.z);
        vv[h][d + 3] = bf2f(c.w);
        if (haspos) {
            ushort4 qq = *(const ushort4*)(qkv + (size_t)mp * 3072 + e);
            ushort4 pq = *(const ushort4*)(pbuf + (size_t)mp * 1024 + e);
            float4 vv4 = *(const float4*)(vbias + e);
            qv[h][d + 0] = bf2f(qq.x) + vv4.x;
            qv[h][d + 1] = bf2f(qq.y) + vv4.y;
            qv[h][d + 2] = bf2f(qq.z) + vv4.z;
            qv[h][d + 3] = bf2f(qq.w) + vv4.w;
            pp[h][d + 0] = bf2f(pq.x);
            pp[h][d + 1] = bf2f(pq.y);
            pp[h][d + 2] = bf2f(pq.z);
            pp[h][d + 3] = bf2f(pq.w);
        } else {
            qv[h][d + 0] = 0.f; qv[h][d + 1] = 0.f; qv[h][d + 2] = 0.f; qv[h][d + 3] = 0.f;
            pp[h][d + 0] = 0.f; pp[h][d + 1] = 0.f; pp[h][d + 2] = 0.f; pp[h][d + 3] = 0.f;
        }
    }
    __syncthreads();

    const int sh = tid >> 4;   // score row h
    const int sk = tid & 15;   // score col k'
    float cs = 0.f, ps = 0.f;
#pragma unroll 8
    for (int dd = 0; dd < 64; ++dd) {
        cs += qu[sh][dd] * kk[sk][dd];
        ps += qv[sh][dd] * pp[sk][dd];
    }
    float score = (cs + ps) * 0.03125f;   // /sqrt(1024)
    score = (masks[m] != 0) ? score : 1e-9f;

    // softmax over sk within contiguous 16-lane groups
    float mx = score;
#pragma unroll
    for (int o = 8; o; o >>= 1) mx = fmaxf(mx, __shfl_xor(mx, o, 64));
    float ex = __expf(score - mx);
    float sum = ex;
#pragma unroll
    for (int o = 8; o; o >>= 1) sum += __shfl_xor(sum, o, 64);
    at[sh][sk] = ex / sum;
    __syncthreads();

    // ctx[h][d] = sum_k at[h][k]*v[k][d]; write in output-GEMM layout:
    // row = b2*2048 + h*128 + t2/16, col = (t2%16)*64 + d
#pragma unroll
    for (int j = 0; j < 4; ++j) {
        const int idx = tid + j * 256;
        const int hh = idx >> 6;
        const int dd2 = idx & 63;
        float s = 0.f;
#pragma unroll
        for (int k2 = 0; k2 < 16; ++k2)
            s += at[hh][k2] * vv[k2][dd2];
        const size_t orow = (size_t)b2 * 2048 + hh * 128 + (t2 >> 4);
        ctx[orow * 1024 + (t2 & 15) * 64 + dd2] = f2bf(s);
    }
}

extern "C" void kernel_launch(void* const* d_in, const int* in_sizes, int n_in,
                              void* d_out, int out_size, void* d_ws, size_t ws_size,
                              hipStream_t stream)
{
    (void)in_sizes; (void)n_in; (void)out_size; (void)ws_size;
    const float* inputs = (const float*)d_in[0];
    const float* pos    = (const float*)d_in[1];
    const int*   masks  = (const int*)d_in[2];
    const float* Wq = (const float*)d_in[3];
    const float* bq = (const float*)d_in[4];
    const float* Wk = (const float*)d_in[5];
    const float* bk = (const float*)d_in[6];
    const float* Wv = (const float*)d_in[7];
    const float* bv = (const float*)d_in[8];
    const float* Wp = (const float*)d_in[9];
    const float* Wo = (const float*)d_in[10];
    const float* bo = (const float*)d_in[11];
    const float* ub = (const float*)d_in[12];
    const float* vb = (const float*)d_in[13];

    // ws layout:
    //   [0,10MB)      WqT|WkT|WvT|WpT|WoT  (bf16 [N][K], contiguous -> fused QKV B)
    //   [10MB,+64KB)  biascat (f32[3072])
    //   S1 (32MB): pos_bf16 -> inputs_bf16 -> ctx   (sequential reuse)
    //   S2 (32MB): pbuf  (pos @ Wp, bf16)
    //   S3 (96MB): qkv   ([16384][3072] bf16)
    char* ws = (char*)d_ws;
    const size_t WT_SZ = (size_t)1024 * 1024 * 2;
    ushort* WqT = (ushort*)(ws);
    ushort* WkT = (ushort*)(ws + 1 * WT_SZ);
    ushort* WvT = (ushort*)(ws + 2 * WT_SZ);
    ushort* WpT = (ushort*)(ws + 3 * WT_SZ);
    ushort* WoT = (ushort*)(ws + 4 * WT_SZ);
    float*  biascat = (float*)(ws + 5 * WT_SZ);
    char* bufs = ws + 5 * WT_SZ + 65536;
    const size_t S_SZ = (size_t)16384 * 1024 * 2;       // 32MB
    ushort* S1 = (ushort*)(bufs);
    ushort* S2 = (ushort*)(bufs + S_SZ);
    ushort* S3 = (ushort*)(bufs + 2 * S_SZ);            // 96MB

    dim3 blk(256);
    dim3 tgrid(32, 32);

    // weights + biases
    transpose_convert_k<<<tgrid, blk, 0, stream>>>(Wq, WqT, 1024, 1024);
    transpose_convert_k<<<tgrid, blk, 0, stream>>>(Wk, WkT, 1024, 1024);
    transpose_convert_k<<<tgrid, blk, 0, stream>>>(Wv, WvT, 1024, 1024);
    transpose_convert_k<<<tgrid, blk, 0, stream>>>(Wp, WpT, 1024, 1024);
    transpose_convert_k<<<tgrid, blk, 0, stream>>>(Wo, WoT, 1024, 1024);
    bias_concat_k<<<dim3(12), blk, 0, stream>>>(bq, bk, bv, biascat);

    // pos -> bf16 (S1); P-GEMM -> S2
    conv_bf16_k<<<dim3(8192), blk, 0, stream>>>(pos, S1);
    gemm6_k<0, 1><<<dim3(4, 128), dim3(512), 0, stream>>>(S1, WpT, nullptr, S2, 1024, 1024);

    // inputs -> bf16 (S1); fused QKV GEMM -> S3
    conv_bf16_k<<<dim3(8192), blk, 0, stream>>>(inputs, S1);
    gemm6_k<1, 1><<<dim3(12, 128), dim3(512), 0, stream>>>(S1, WqT, biascat, S3, 3072, 1024);

    // attention -> ctx (S1, overwrites inputs_bf16)
    attn_k<<<dim3(16384), blk, 0, stream>>>(S3, S2, ub, vb, masks, S1);

    // out = ctx @ Wo + bo  (f32)
    gemm6_k<1, 0><<<dim3(4, 128), dim3(512), 0, stream>>>(S1, WoT, bo, (float*)d_out, 1024, 1024);
}

// Round 7
// 290.498 us; speedup vs baseline: 1.1710x; 1.1710x over previous
//
#include <hip/hip_runtime.h>

// RelativeMultiHeadAttention (B=8, T=2048, D_MODEL=1024, H=16, D_HEAD=64)
// Round 7: MFMA-based attention (frags direct from global, tiny LDS P-tile),
// GEMM kept from Round 6 (128x256, 3-region LDS, counted VMC(3)).
//
// rel_shift: shifted[m] = pos_score[f=m+8 over flat (b*(T+1)+t)]:
//   b_s = f/2049, t_s = f%2049; zero block if t_s==0 else source (b_s, t_s-1).

typedef __attribute__((ext_vector_type(8))) short short8;
typedef __attribute__((ext_vector_type(4))) float f32x4;

__device__ __forceinline__ ushort f2bf(float f) {
    unsigned u = __float_as_uint(f);
    u += 0x7FFFu + ((u >> 16) & 1u);   // round-to-nearest-even
    return (ushort)(u >> 16);
}
__device__ __forceinline__ float bf2f(ushort u) {
    return __uint_as_float(((unsigned)u) << 16);
}

typedef const unsigned int __attribute__((address_space(1)))* gas_t;
typedef unsigned int __attribute__((address_space(3)))* las_t;
__device__ __forceinline__ void gl_lds16(const ushort* g, ushort* l) {
    __builtin_amdgcn_global_load_lds((gas_t)g, (las_t)l, 16, 0, 0);
}

// ---------------- f32 -> bf16 convert (8 elems/thread) ----------------
__global__ __launch_bounds__(256)
void conv_bf16_k(const float* __restrict__ in, ushort* __restrict__ out)
{
    const size_t i = ((size_t)blockIdx.x * 256 + threadIdx.x) * 8;
    float4 a = *(const float4*)(in + i);
    float4 b = *(const float4*)(in + i + 4);
    short8 o = {(short)f2bf(a.x), (short)f2bf(a.y), (short)f2bf(a.z), (short)f2bf(a.w),
                (short)f2bf(b.x), (short)f2bf(b.y), (short)f2bf(b.z), (short)f2bf(b.w)};
    *(short8*)(out + i) = o;
}

// ---------------- Wt[n][k] = bf16(W[k][n]) ----------------
__global__ __launch_bounds__(256)
void transpose_convert_k(const float* __restrict__ W, ushort* __restrict__ Wt, int K, int N)
{
    __shared__ float tile[32][33];
    const int tx = threadIdx.x & 31;
    const int ty = threadIdx.x >> 5;   // 0..7
    const int n0 = blockIdx.x * 32;
    const int k0 = blockIdx.y * 32;
#pragma unroll
    for (int i = 0; i < 4; ++i)
        tile[ty + i * 8][tx] = W[(size_t)(k0 + ty + i * 8) * N + n0 + tx];
    __syncthreads();
#pragma unroll
    for (int i = 0; i < 4; ++i)
        Wt[(size_t)(n0 + ty + i * 8) * K + k0 + tx] = f2bf(tile[tx][ty + i * 8]);
}

// ---------------- bias concat [bq;bk;bv] ----------------
__global__ __launch_bounds__(256)
void bias_concat_k(const float* __restrict__ b0, const float* __restrict__ b1,
                   const float* __restrict__ b2, float* __restrict__ out)
{
    const int i = blockIdx.x * 256 + threadIdx.x;   // 0..3071
    const int s = i >> 10;
    const int j = i & 1023;
    out[i] = (s == 0) ? b0[j] : (s == 1) ? b1[j] : b2[j];
}

// ======== 128x256 GEMM, BK=32, 3-region LDS (unchanged from R6) ========
#define VMC(n) asm volatile("s_waitcnt vmcnt(" #n ")" ::: "memory")

template<int HAS_BIAS, int OUT_BF16>
__global__ __launch_bounds__(512, 4)
void gemm6_k(const ushort* __restrict__ A, const ushort* __restrict__ Bt,
             const float* __restrict__ bias, void* __restrict__ Cv,
             int N, int K)
{
    __shared__ ushort As[3 * 4096];   // 24KB: [3][128][32]
    __shared__ ushort Bs[3 * 8192];   // 48KB: [3][256][32]
    const int tid = threadIdx.x;
    const int l = tid & 63;
    const int w = tid >> 6;
    const int wr = w >> 2;             // 0..1 (m 64-half)
    const int wc = w & 3;              // 0..3 (n 64-quarter)

    const int gx = gridDim.x;
    const int lin = blockIdx.y * gx + blockIdx.x;
    const int xcd = lin & 7;
    const int idx = lin >> 3;
    const int hb = gridDim.y >> 3;
    const int sxc = gx >> 2;
    const int g4 = idx >> 4;
    const int li = idx & 15;
    const int bx = (g4 % sxc) * 4 + (li & 3);
    const int by = xcd * hb + (g4 / sxc) * 4 + (li >> 2);
    const int bm = by * 128;
    const int bn = bx * 256;
    const int NT = K >> 5;

    const int srow = tid >> 2;
    const int scol = ((tid & 3) ^ ((tid >> 3) & 3)) * 8;
    const ushort* Ag  = A  + (size_t)(bm + srow) * K + scol;
    const ushort* Bg  = Bt + (size_t)(bn + srow) * K + scol;
    const ushort* Bg2 = Bg + (size_t)128 * K;
    const int lw = w * 512;

    const int lr = l & 15;
    const int fb = (((l >> 4) ^ ((l >> 1) & 3)) * 8);
    const int laneA = (wr * 64 + lr) * 32 + fb;
    const int laneB = (wc * 64 + lr) * 32 + fb;

    f32x4 acc[4][4];
#pragma unroll
    for (int i = 0; i < 4; ++i)
#pragma unroll
        for (int n = 0; n < 4; ++n)
            acc[i][n] = (f32x4){0.f, 0.f, 0.f, 0.f};

#define STAGE6(tt, rg) do { \
    ushort* ha = As + (rg) * 4096 + lw; \
    ushort* hbp = Bs + (rg) * 8192 + lw; \
    const size_t ko = (size_t)(tt) * 32; \
    gl_lds16(Ag + ko, ha); \
    gl_lds16(Bg + ko, hbp); \
    gl_lds16(Bg2 + ko, hbp + 4096); \
} while (0)

    STAGE6(0, 0);
    STAGE6(1, 1);
    VMC(3);
    __builtin_amdgcn_s_barrier();
    __builtin_amdgcn_sched_barrier(0);

    int cur = 0, stg = 2;
    for (int t = 0; t < NT; ++t) {
        if (t + 2 < NT) STAGE6(t + 2, stg);
        const ushort* ap = As + cur * 4096 + laneA;
        const ushort* bp = Bs + cur * 8192 + laneB;
        short8 af[4], bf4[4];
#pragma unroll
        for (int m = 0; m < 4; ++m) af[m] = *(const short8*)(ap + m * 512);
#pragma unroll
        for (int n = 0; n < 4; ++n) bf4[n] = *(const short8*)(bp + n * 512);
        asm volatile("s_waitcnt lgkmcnt(0)" ::: "memory");
        __builtin_amdgcn_sched_barrier(0);
        __builtin_amdgcn_s_setprio(1);
#pragma unroll
        for (int m = 0; m < 4; ++m)
#pragma unroll
            for (int n = 0; n < 4; ++n)
                acc[m][n] = __builtin_amdgcn_mfma_f32_16x16x32_bf16(af[m], bf4[n], acc[m][n], 0, 0, 0);
        __builtin_amdgcn_s_setprio(0);
        __builtin_amdgcn_sched_barrier(0);
        if (t < NT - 2) { VMC(3); }
        else if (t == NT - 2) { VMC(0); }
        if (t < NT - 1) {
            __builtin_amdgcn_s_barrier();
            __builtin_amdgcn_sched_barrier(0);
        }
        cur = (cur == 2) ? 0 : cur + 1;
        stg = (stg == 2) ? 0 : stg + 1;
    }
#undef STAGE6

    const int cr = (l >> 4) * 4;
    const int cc = l & 15;
    float bv[4];
#pragma unroll
    for (int n = 0; n < 4; ++n)
        bv[n] = HAS_BIAS ? bias[bn + wc * 64 + n * 16 + cc] : 0.f;
#pragma unroll
    for (int m = 0; m < 4; ++m) {
#pragma unroll
        for (int n = 0; n < 4; ++n) {
            const int col = bn + wc * 64 + n * 16 + cc;
#pragma unroll
            for (int r = 0; r < 4; ++r) {
                const int row = bm + wr * 64 + m * 16 + cr + r;
                float v = acc[m][n][r] + bv[n];
                if (OUT_BF16) ((ushort*)Cv)[(size_t)row * N + col] = f2bf(v);
                else          ((float*)Cv)[(size_t)row * N + col] = v;
            }
        }
    }
}

// ---------------- MFMA attention: 1 wave = 1 timestep ----------------
// qkv: [16384][3072] (q|k|v), pbuf: [16384][1024]
// Frag convention (verified via GEMM): lane l holds operand[l&15][(l>>4)*8+e];
// D[row][col]: row=(l>>4)*4+r, col=l&15.
// Scores: S = mfma(qu0,k0)+mfma(qu1,k1)+mfma(qv0,p0)+mfma(qv1,p1) (one acc).
// Softmax over col (lanes l&15). PV: A=P via LDS f32 tile (stride 20),
// B=V^T frags via scalar u16 global loads; K padded to 32 with zero frags.
__global__ __launch_bounds__(256)
void attn2_k(const ushort* __restrict__ qkv, const ushort* __restrict__ pbuf,
             const float* __restrict__ ubias, const float* __restrict__ vbias,
             const int* __restrict__ masks, ushort* __restrict__ ctx)
{
    __shared__ __align__(16) float Pl[4][16 * 20];   // per-wave P tile, stride 20

    const int tid = threadIdx.x;
    const int w = tid >> 6;
    const int l = tid & 63;
    const int m = blockIdx.x * 4 + w;
    const int b2 = m >> 11;
    const int t2 = m & 2047;
    const int f  = m + 8;
    const int bs = f / 2049;
    const int ts = f - bs * 2049;
    const bool haspos = (ts != 0);
    const int mp = bs * 2048 + ts - 1;

    const int lr = l & 15;     // operand row (head index for frags)
    const int g  = l >> 4;     // k-group
    const int ko = g * 8;      // k offset within 32-chunk

    const ushort* qb = qkv + (size_t)m * 3072;

    // load + build frags
    short8 quf[2], kf[2], qvf[2], pf[2];
#pragma unroll
    for (int c = 0; c < 2; ++c) {
        const int off = lr * 64 + c * 32 + ko;
        short8 q = *(const short8*)(qb + off);
        kf[c]    = *(const short8*)(qb + 1024 + off);
        float4 u0 = *(const float4*)(ubias + off);
        float4 u1 = *(const float4*)(ubias + off + 4);
        quf[c] = (short8){
            (short)f2bf(bf2f((ushort)q[0]) + u0.x), (short)f2bf(bf2f((ushort)q[1]) + u0.y),
            (short)f2bf(bf2f((ushort)q[2]) + u0.z), (short)f2bf(bf2f((ushort)q[3]) + u0.w),
            (short)f2bf(bf2f((ushort)q[4]) + u1.x), (short)f2bf(bf2f((ushort)q[5]) + u1.y),
            (short)f2bf(bf2f((ushort)q[6]) + u1.z), (short)f2bf(bf2f((ushort)q[7]) + u1.w)};
    }
    if (haspos) {
        const ushort* qmp = qkv + (size_t)mp * 3072;
        const ushort* pp  = pbuf + (size_t)mp * 1024;
#pragma unroll
        for (int c = 0; c < 2; ++c) {
            const int off = lr * 64 + c * 32 + ko;
            short8 q = *(const short8*)(qmp + off);
            pf[c]    = *(const short8*)(pp + off);
            float4 v0 = *(const float4*)(vbias + off);
            float4 v1 = *(const float4*)(vbias + off + 4);
            qvf[c] = (short8){
                (short)f2bf(bf2f((ushort)q[0]) + v0.x), (short)f2bf(bf2f((ushort)q[1]) + v0.y),
                (short)f2bf(bf2f((ushort)q[2]) + v0.z), (short)f2bf(bf2f((ushort)q[3]) + v0.w),
                (short)f2bf(bf2f((ushort)q[4]) + v1.x), (short)f2bf(bf2f((ushort)q[5]) + v1.y),
                (short)f2bf(bf2f((ushort)q[6]) + v1.z), (short)f2bf(bf2f((ushort)q[7]) + v1.w)};
        }
    }

    // scores (content + pos in one accumulator)
    f32x4 s = (f32x4){0.f, 0.f, 0.f, 0.f};
    s = __builtin_amdgcn_mfma_f32_16x16x32_bf16(quf[0], kf[0], s, 0, 0, 0);
    s = __builtin_amdgcn_mfma_f32_16x16x32_bf16(quf[1], kf[1], s, 0, 0, 0);
    if (haspos) {
        s = __builtin_amdgcn_mfma_f32_16x16x32_bf16(qvf[0], pf[0], s, 0, 0, 0);
        s = __builtin_amdgcn_mfma_f32_16x16x32_bf16(qvf[1], pf[1], s, 0, 0, 0);
    }

    // scale + mask
    const bool mk = (masks[m] != 0);
    float sc[4];
#pragma unroll
    for (int r = 0; r < 4; ++r)
        sc[r] = mk ? s[r] * 0.03125f : 1e-9f;

    // softmax over cols (lanes within 16-lane group), per reg
    float mx[4], ex[4], sm[4];
#pragma unroll
    for (int r = 0; r < 4; ++r) {
        mx[r] = sc[r];
#pragma unroll
        for (int o = 8; o; o >>= 1) mx[r] = fmaxf(mx[r], __shfl_xor(mx[r], o, 64));
        ex[r] = __expf(sc[r] - mx[r]);
        sm[r] = ex[r];
#pragma unroll
        for (int o = 8; o; o >>= 1) sm[r] += __shfl_xor(sm[r], o, 64);
    }

    // write P to LDS: P[h1][h2] at pw[h1*20 + h2]; h1=g*4+r, h2=lr
    float* pw = Pl[w];
#pragma unroll
    for (int r = 0; r < 4; ++r)
        pw[(g * 4 + r) * 20 + lr] = ex[r] / sm[r];

    // read P A-frag: lane needs P[l&15][g*8+j], g>=2 -> 0
    short8 pa;
    if (g < 2) {
        float4 p0 = *(const float4*)(pw + lr * 20 + g * 8);
        float4 p1 = *(const float4*)(pw + lr * 20 + g * 8 + 4);
        pa = (short8){(short)f2bf(p0.x), (short)f2bf(p0.y), (short)f2bf(p0.z), (short)f2bf(p0.w),
                      (short)f2bf(p1.x), (short)f2bf(p1.y), (short)f2bf(p1.z), (short)f2bf(p1.w)};
    } else {
        pa = (short8){0, 0, 0, 0, 0, 0, 0, 0};
    }

    // PV: 4 n-chunks of 16 cols; B[n=d0+lr][k=ko+j] = V[ko+j][d0+lr]
    const ushort* vb0 = qb + 2048;
    const size_t orow_base = (size_t)b2 * 2048 + (t2 >> 4);
    const int ocol_base = (t2 & 15) * 64;
#pragma unroll
    for (int n = 0; n < 4; ++n) {
        const int d0 = n * 16;
        short8 vf;
        if (g < 2) {
#pragma unroll
            for (int j = 0; j < 8; ++j)
                vf[j] = (short)vb0[(ko + j) * 64 + d0 + lr];
        } else {
            vf = (short8){0, 0, 0, 0, 0, 0, 0, 0};
        }
        f32x4 o = (f32x4){0.f, 0.f, 0.f, 0.f};
        o = __builtin_amdgcn_mfma_f32_16x16x32_bf16(pa, vf, o, 0, 0, 0);
#pragma unroll
        for (int r = 0; r < 4; ++r) {
            const int h1 = g * 4 + r;
            ctx[(orow_base + (size_t)h1 * 128) * 1024 + ocol_base + d0 + lr] = f2bf(o[r]);
        }
    }
}

extern "C" void kernel_launch(void* const* d_in, const int* in_sizes, int n_in,
                              void* d_out, int out_size, void* d_ws, size_t ws_size,
                              hipStream_t stream)
{
    (void)in_sizes; (void)n_in; (void)out_size; (void)ws_size;
    const float* inputs = (const float*)d_in[0];
    const float* pos    = (const float*)d_in[1];
    const int*   masks  = (const int*)d_in[2];
    const float* Wq = (const float*)d_in[3];
    const float* bq = (const float*)d_in[4];
    const float* Wk = (const float*)d_in[5];
    const float* bk = (const float*)d_in[6];
    const float* Wv = (const float*)d_in[7];
    const float* bv = (const float*)d_in[8];
    const float* Wp = (const float*)d_in[9];
    const float* Wo = (const float*)d_in[10];
    const float* bo = (const float*)d_in[11];
    const float* ub = (const float*)d_in[12];
    const float* vb = (const float*)d_in[13];

    // ws layout:
    //   [0,10MB)      WqT|WkT|WvT|WpT|WoT  (bf16 [N][K])
    //   [10MB,+64KB)  biascat (f32[3072])
    //   S1 (32MB): pos_bf16 -> inputs_bf16 -> ctx
    //   S2 (32MB): pbuf  (pos @ Wp, bf16)
    //   S3 (96MB): qkv   ([16384][3072] bf16)
    char* ws = (char*)d_ws;
    const size_t WT_SZ = (size_t)1024 * 1024 * 2;
    ushort* WqT = (ushort*)(ws);
    ushort* WkT = (ushort*)(ws + 1 * WT_SZ);
    ushort* WvT = (ushort*)(ws + 2 * WT_SZ);
    ushort* WpT = (ushort*)(ws + 3 * WT_SZ);
    ushort* WoT = (ushort*)(ws + 4 * WT_SZ);
    float*  biascat = (float*)(ws + 5 * WT_SZ);
    char* bufs = ws + 5 * WT_SZ + 65536;
    const size_t S_SZ = (size_t)16384 * 1024 * 2;       // 32MB
    ushort* S1 = (ushort*)(bufs);
    ushort* S2 = (ushort*)(bufs + S_SZ);
    ushort* S3 = (ushort*)(bufs + 2 * S_SZ);            // 96MB

    dim3 blk(256);
    dim3 tgrid(32, 32);

    transpose_convert_k<<<tgrid, blk, 0, stream>>>(Wq, WqT, 1024, 1024);
    transpose_convert_k<<<tgrid, blk, 0, stream>>>(Wk, WkT, 1024, 1024);
    transpose_convert_k<<<tgrid, blk, 0, stream>>>(Wv, WvT, 1024, 1024);
    transpose_convert_k<<<tgrid, blk, 0, stream>>>(Wp, WpT, 1024, 1024);
    transpose_convert_k<<<tgrid, blk, 0, stream>>>(Wo, WoT, 1024, 1024);
    bias_concat_k<<<dim3(12), blk, 0, stream>>>(bq, bk, bv, biascat);

    conv_bf16_k<<<dim3(8192), blk, 0, stream>>>(pos, S1);
    gemm6_k<0, 1><<<dim3(4, 128), dim3(512), 0, stream>>>(S1, WpT, nullptr, S2, 1024, 1024);

    conv_bf16_k<<<dim3(8192), blk, 0, stream>>>(inputs, S1);
    gemm6_k<1, 1><<<dim3(12, 128), dim3(512), 0, stream>>>(S1, WqT, biascat, S3, 3072, 1024);

    attn2_k<<<dim3(4096), blk, 0, stream>>>(S3, S2, ub, vb, masks, S1);

    gemm6_k<1, 0><<<dim3(4, 128), dim3(512), 0, stream>>>(S1, WoT, bo, (float*)d_out, 1024, 1024);
}

// Round 8
// 286.296 us; speedup vs baseline: 1.1882x; 1.0147x over previous
//
#include <hip/hip_runtime.h>

// RelativeMultiHeadAttention (B=8, T=2048, D_MODEL=1024, H=16, D_HEAD=64)
// Round 8: GEMM with compiler-scheduled overlap: full NT=32 unroll, one
// barrier/tile, lgkmcnt(0) pre-barrier (region safety), VMC(3) counted,
// MFMA(t-1) free to interleave with STAGE/ds_reads of tile t.
// Attention: MFMA-based (R7). rel_shift: shifted[m]=pos_score[f=m+8 flat
// (b*(T+1)+t)]: b_s=f/2049, t_s=f%2049; zero if t_s==0 else (b_s,t_s-1).

typedef __attribute__((ext_vector_type(8))) short short8;
typedef __attribute__((ext_vector_type(4))) float f32x4;

__device__ __forceinline__ ushort f2bf(float f) {
    unsigned u = __float_as_uint(f);
    u += 0x7FFFu + ((u >> 16) & 1u);   // round-to-nearest-even
    return (ushort)(u >> 16);
}
__device__ __forceinline__ float bf2f(ushort u) {
    return __uint_as_float(((unsigned)u) << 16);
}

typedef const unsigned int __attribute__((address_space(1)))* gas_t;
typedef unsigned int __attribute__((address_space(3)))* las_t;
__device__ __forceinline__ void gl_lds16(const ushort* g, ushort* l) {
    __builtin_amdgcn_global_load_lds((gas_t)g, (las_t)l, 16, 0, 0);
}

// ---------------- f32 -> bf16 convert (8 elems/thread) ----------------
__global__ __launch_bounds__(256)
void conv_bf16_k(const float* __restrict__ in, ushort* __restrict__ out)
{
    const size_t i = ((size_t)blockIdx.x * 256 + threadIdx.x) * 8;
    float4 a = *(const float4*)(in + i);
    float4 b = *(const float4*)(in + i + 4);
    short8 o = {(short)f2bf(a.x), (short)f2bf(a.y), (short)f2bf(a.z), (short)f2bf(a.w),
                (short)f2bf(b.x), (short)f2bf(b.y), (short)f2bf(b.z), (short)f2bf(b.w)};
    *(short8*)(out + i) = o;
}

// ---------------- Wt[n][k] = bf16(W[k][n]) ----------------
__global__ __launch_bounds__(256)
void transpose_convert_k(const float* __restrict__ W, ushort* __restrict__ Wt, int K, int N)
{
    __shared__ float tile[32][33];
    const int tx = threadIdx.x & 31;
    const int ty = threadIdx.x >> 5;   // 0..7
    const int n0 = blockIdx.x * 32;
    const int k0 = blockIdx.y * 32;
#pragma unroll
    for (int i = 0; i < 4; ++i)
        tile[ty + i * 8][tx] = W[(size_t)(k0 + ty + i * 8) * N + n0 + tx];
    __syncthreads();
#pragma unroll
    for (int i = 0; i < 4; ++i)
        Wt[(size_t)(n0 + ty + i * 8) * K + k0 + tx] = f2bf(tile[tx][ty + i * 8]);
}

// ---------------- bias concat [bq;bk;bv] ----------------
__global__ __launch_bounds__(256)
void bias_concat_k(const float* __restrict__ b0, const float* __restrict__ b1,
                   const float* __restrict__ b2, float* __restrict__ out)
{
    const int i = blockIdx.x * 256 + threadIdx.x;   // 0..3071
    const int s = i >> 10;
    const int j = i & 1023;
    out[i] = (s == 0) ? b0[j] : (s == 1) ? b1[j] : b2[j];
}

// ======== 128x256 GEMM, K=1024 hardcoded (NT=32), 3-region LDS ========
// 512 thr = 8 waves (2x4); per-wave C: 64x64 (4x4 frags), acc 64 AGPR.
// LDS: A [3][128][32]=24KB + B [3][256][32]=48KB = 72KB -> 2 blocks/CU.
// Swizzle: colbyte ^= ((row>>1)&3)<<4 (staging-source AND ds_read side).
// Body t (full unroll, regions cur=t%3, stg=(t+2)%3):
//   STAGE(t+2); ds_read A4+B4; VMC(3) [lands t+1]; lgkmcnt(0) [reads done
//   before barrier -> next overwrite safe]; s_barrier; sched_barrier;
//   16 MFMA (interleaves with NEXT body's STAGE/ds_reads in the unrolled
//   straight-line region). Tail: VMC(0)@t=30.

#define VMC(n) asm volatile("s_waitcnt vmcnt(" #n ")" ::: "memory")
#define KDIM 1024

template<int HAS_BIAS, int OUT_BF16>
__global__ __launch_bounds__(512, 4)
void gemm7_k(const ushort* __restrict__ A, const ushort* __restrict__ Bt,
             const float* __restrict__ bias, void* __restrict__ Cv,
             int N)
{
    __shared__ ushort As[3 * 4096];   // 24KB: [3][128][32]
    __shared__ ushort Bs[3 * 8192];   // 48KB: [3][256][32]
    const int tid = threadIdx.x;
    const int l = tid & 63;
    const int w = tid >> 6;
    const int wr = w >> 2;             // 0..1 (m 64-half)
    const int wc = w & 3;              // 0..3 (n 64-quarter)

    // XCD/L2-aware bijective remap (gx%4==0, gy%8==0)
    const int gx = gridDim.x;
    const int lin = blockIdx.y * gx + blockIdx.x;
    const int xcd = lin & 7;
    const int idx = lin >> 3;
    const int hb = gridDim.y >> 3;
    const int sxc = gx >> 2;
    const int g4 = idx >> 4;
    const int li = idx & 15;
    const int bx = (g4 % sxc) * 4 + (li & 3);
    const int by = xcd * hb + (g4 / sxc) * 4 + (li >> 2);
    const int bm = by * 128;
    const int bn = bx * 256;

    const int srow = tid >> 2;
    const int scol = ((tid & 3) ^ ((tid >> 3) & 3)) * 8;
    const ushort* Ag  = A  + (size_t)(bm + srow) * KDIM + scol;
    const ushort* Bg  = Bt + (size_t)(bn + srow) * KDIM + scol;
    const ushort* Bg2 = Bg + (size_t)128 * KDIM;
    const int lw = w * 512;

    const int lr = l & 15;
    const int fb = (((l >> 4) ^ ((l >> 1) & 3)) * 8);
    const int laneA = (wr * 64 + lr) * 32 + fb;
    const int laneB = (wc * 64 + lr) * 32 + fb;

    f32x4 acc[4][4];
#pragma unroll
    for (int i = 0; i < 4; ++i)
#pragma unroll
        for (int n = 0; n < 4; ++n)
            acc[i][n] = (f32x4){0.f, 0.f, 0.f, 0.f};

#define STAGE7(tt, rg) do { \
    ushort* ha = As + (rg) * 4096 + lw; \
    ushort* hbp = Bs + (rg) * 8192 + lw; \
    const size_t ko = (size_t)(tt) * 32; \
    gl_lds16(Ag + ko, ha); \
    gl_lds16(Bg + ko, hbp); \
    gl_lds16(Bg2 + ko, hbp + 4096); \
} while (0)

    // prologue: stage t0->r0, t1->r1; land t0; barrier
    STAGE7(0, 0);
    STAGE7(1, 1);
    VMC(3);
    __builtin_amdgcn_s_barrier();
    __builtin_amdgcn_sched_barrier(0);

#pragma unroll
    for (int t = 0; t < 32; ++t) {
        const int cur = t % 3;
        const int stg = (t + 2) % 3;
        if (t + 2 < 32) STAGE7(t + 2, stg);
        const ushort* ap = As + cur * 4096 + laneA;
        const ushort* bp = Bs + cur * 8192 + laneB;
        short8 af[4], bf4[4];
#pragma unroll
        for (int m = 0; m < 4; ++m) af[m] = *(const short8*)(ap + m * 512);
#pragma unroll
        for (int n = 0; n < 4; ++n) bf4[n] = *(const short8*)(bp + n * 512);
        if (t < 30) { VMC(3); }
        else if (t == 30) { VMC(0); }
        asm volatile("s_waitcnt lgkmcnt(0)" ::: "memory");
        __builtin_amdgcn_s_barrier();
        __builtin_amdgcn_sched_barrier(0);
#pragma unroll
        for (int m = 0; m < 4; ++m)
#pragma unroll
            for (int n = 0; n < 4; ++n)
                acc[m][n] = __builtin_amdgcn_mfma_f32_16x16x32_bf16(af[m], bf4[n], acc[m][n], 0, 0, 0);
    }
#undef STAGE7

    // epilogue: C/D layout col=lane&15, row=(lane>>4)*4+reg
    const int cr = (l >> 4) * 4;
    const int cc = l & 15;
    float bv[4];
#pragma unroll
    for (int n = 0; n < 4; ++n)
        bv[n] = HAS_BIAS ? bias[bn + wc * 64 + n * 16 + cc] : 0.f;
#pragma unroll
    for (int m = 0; m < 4; ++m) {
#pragma unroll
        for (int n = 0; n < 4; ++n) {
            const int col = bn + wc * 64 + n * 16 + cc;
#pragma unroll
            for (int r = 0; r < 4; ++r) {
                const int row = bm + wr * 64 + m * 16 + cr + r;
                float v = acc[m][n][r] + bv[n];
                if (OUT_BF16) ((ushort*)Cv)[(size_t)row * N + col] = f2bf(v);
                else          ((float*)Cv)[(size_t)row * N + col] = v;
            }
        }
    }
}

// ---------------- MFMA attention: 1 wave = 1 timestep (R7) ----------------
__global__ __launch_bounds__(256)
void attn2_k(const ushort* __restrict__ qkv, const ushort* __restrict__ pbuf,
             const float* __restrict__ ubias, const float* __restrict__ vbias,
             const int* __restrict__ masks, ushort* __restrict__ ctx)
{
    __shared__ __align__(16) float Pl[4][16 * 20];   // per-wave P tile, stride 20

    const int tid = threadIdx.x;
    const int w = tid >> 6;
    const int l = tid & 63;
    const int m = blockIdx.x * 4 + w;
    const int b2 = m >> 11;
    const int t2 = m & 2047;
    const int f  = m + 8;
    const int bs = f / 2049;
    const int ts = f - bs * 2049;
    const bool haspos = (ts != 0);
    const int mp = bs * 2048 + ts - 1;

    const int lr = l & 15;
    const int g  = l >> 4;
    const int ko = g * 8;

    const ushort* qb = qkv + (size_t)m * 3072;

    short8 quf[2], kf[2], qvf[2], pf[2];
#pragma unroll
    for (int c = 0; c < 2; ++c) {
        const int off = lr * 64 + c * 32 + ko;
        short8 q = *(const short8*)(qb + off);
        kf[c]    = *(const short8*)(qb + 1024 + off);
        float4 u0 = *(const float4*)(ubias + off);
        float4 u1 = *(const float4*)(ubias + off + 4);
        quf[c] = (short8){
            (short)f2bf(bf2f((ushort)q[0]) + u0.x), (short)f2bf(bf2f((ushort)q[1]) + u0.y),
            (short)f2bf(bf2f((ushort)q[2]) + u0.z), (short)f2bf(bf2f((ushort)q[3]) + u0.w),
            (short)f2bf(bf2f((ushort)q[4]) + u1.x), (short)f2bf(bf2f((ushort)q[5]) + u1.y),
            (short)f2bf(bf2f((ushort)q[6]) + u1.z), (short)f2bf(bf2f((ushort)q[7]) + u1.w)};
    }
    if (haspos) {
        const ushort* qmp = qkv + (size_t)mp * 3072;
        const ushort* pp  = pbuf + (size_t)mp * 1024;
#pragma unroll
        for (int c = 0; c < 2; ++c) {
            const int off = lr * 64 + c * 32 + ko;
            short8 q = *(const short8*)(qmp + off);
            pf[c]    = *(const short8*)(pp + off);
            float4 v0 = *(const float4*)(vbias + off);
            float4 v1 = *(const float4*)(vbias + off + 4);
            qvf[c] = (short8){
                (short)f2bf(bf2f((ushort)q[0]) + v0.x), (short)f2bf(bf2f((ushort)q[1]) + v0.y),
                (short)f2bf(bf2f((ushort)q[2]) + v0.z), (short)f2bf(bf2f((ushort)q[3]) + v0.w),
                (short)f2bf(bf2f((ushort)q[4]) + v1.x), (short)f2bf(bf2f((ushort)q[5]) + v1.y),
                (short)f2bf(bf2f((ushort)q[6]) + v1.z), (short)f2bf(bf2f((ushort)q[7]) + v1.w)};
        }
    }

    f32x4 s = (f32x4){0.f, 0.f, 0.f, 0.f};
    s = __builtin_amdgcn_mfma_f32_16x16x32_bf16(quf[0], kf[0], s, 0, 0, 0);
    s = __builtin_amdgcn_mfma_f32_16x16x32_bf16(quf[1], kf[1], s, 0, 0, 0);
    if (haspos) {
        s = __builtin_amdgcn_mfma_f32_16x16x32_bf16(qvf[0], pf[0], s, 0, 0, 0);
        s = __builtin_amdgcn_mfma_f32_16x16x32_bf16(qvf[1], pf[1], s, 0, 0, 0);
    }

    const bool mk = (masks[m] != 0);
    float sc[4];
#pragma unroll
    for (int r = 0; r < 4; ++r)
        sc[r] = mk ? s[r] * 0.03125f : 1e-9f;

    float mx[4], ex[4], sm[4];
#pragma unroll
    for (int r = 0; r < 4; ++r) {
        mx[r] = sc[r];
#pragma unroll
        for (int o = 8; o; o >>= 1) mx[r] = fmaxf(mx[r], __shfl_xor(mx[r], o, 64));
        ex[r] = __expf(sc[r] - mx[r]);
        sm[r] = ex[r];
#pragma unroll
        for (int o = 8; o; o >>= 1) sm[r] += __shfl_xor(sm[r], o, 64);
    }

    float* pw = Pl[w];
#pragma unroll
    for (int r = 0; r < 4; ++r)
        pw[(g * 4 + r) * 20 + lr] = ex[r] / sm[r];

    short8 pa;
    if (g < 2) {
        float4 p0 = *(const float4*)(pw + lr * 20 + g * 8);
        float4 p1 = *(const float4*)(pw + lr * 20 + g * 8 + 4);
        pa = (short8){(short)f2bf(p0.x), (short)f2bf(p0.y), (short)f2bf(p0.z), (short)f2bf(p0.w),
                      (short)f2bf(p1.x), (short)f2bf(p1.y), (short)f2bf(p1.z), (short)f2bf(p1.w)};
    } else {
        pa = (short8){0, 0, 0, 0, 0, 0, 0, 0};
    }

    const ushort* vb0 = qb + 2048;
    const size_t orow_base = (size_t)b2 * 2048 + (t2 >> 4);
    const int ocol_base = (t2 & 15) * 64;
#pragma unroll
    for (int n = 0; n < 4; ++n) {
        const int d0 = n * 16;
        short8 vf;
        if (g < 2) {
#pragma unroll
            for (int j = 0; j < 8; ++j)
                vf[j] = (short)vb0[(ko + j) * 64 + d0 + lr];
        } else {
            vf = (short8){0, 0, 0, 0, 0, 0, 0, 0};
        }
        f32x4 o = (f32x4){0.f, 0.f, 0.f, 0.f};
        o = __builtin_amdgcn_mfma_f32_16x16x32_bf16(pa, vf, o, 0, 0, 0);
#pragma unroll
        for (int r = 0; r < 4; ++r) {
            const int h1 = g * 4 + r;
            ctx[(orow_base + (size_t)h1 * 128) * 1024 + ocol_base + d0 + lr] = f2bf(o[r]);
        }
    }
}

extern "C" void kernel_launch(void* const* d_in, const int* in_sizes, int n_in,
                              void* d_out, int out_size, void* d_ws, size_t ws_size,
                              hipStream_t stream)
{
    (void)in_sizes; (void)n_in; (void)out_size; (void)ws_size;
    const float* inputs = (const float*)d_in[0];
    const float* pos    = (const float*)d_in[1];
    const int*   masks  = (const int*)d_in[2];
    const float* Wq = (const float*)d_in[3];
    const float* bq = (const float*)d_in[4];
    const float* Wk = (const float*)d_in[5];
    const float* bk = (const float*)d_in[6];
    const float* Wv = (const float*)d_in[7];
    const float* bv = (const float*)d_in[8];
    const float* Wp = (const float*)d_in[9];
    const float* Wo = (const float*)d_in[10];
    const float* bo = (const float*)d_in[11];
    const float* ub = (const float*)d_in[12];
    const float* vb = (const float*)d_in[13];

    // ws layout:
    //   [0,10MB)      WqT|WkT|WvT|WpT|WoT  (bf16 [N][K])
    //   [10MB,+64KB)  biascat (f32[3072])
    //   S1 (32MB): pos_bf16 -> inputs_bf16 -> ctx
    //   S2 (32MB): pbuf  (pos @ Wp, bf16)
    //   S3 (96MB): qkv   ([16384][3072] bf16)
    char* ws = (char*)d_ws;
    const size_t WT_SZ = (size_t)1024 * 1024 * 2;
    ushort* WqT = (ushort*)(ws);
    ushort* WkT = (ushort*)(ws + 1 * WT_SZ);
    ushort* WvT = (ushort*)(ws + 2 * WT_SZ);
    ushort* WpT = (ushort*)(ws + 3 * WT_SZ);
    ushort* WoT = (ushort*)(ws + 4 * WT_SZ);
    float*  biascat = (float*)(ws + 5 * WT_SZ);
    char* bufs = ws + 5 * WT_SZ + 65536;
    const size_t S_SZ = (size_t)16384 * 1024 * 2;       // 32MB
    ushort* S1 = (ushort*)(bufs);
    ushort* S2 = (ushort*)(bufs + S_SZ);
    ushort* S3 = (ushort*)(bufs + 2 * S_SZ);            // 96MB

    dim3 blk(256);
    dim3 tgrid(32, 32);

    transpose_convert_k<<<tgrid, blk, 0, stream>>>(Wq, WqT, 1024, 1024);
    transpose_convert_k<<<tgrid, blk, 0, stream>>>(Wk, WkT, 1024, 1024);
    transpose_convert_k<<<tgrid, blk, 0, stream>>>(Wv, WvT, 1024, 1024);
    transpose_convert_k<<<tgrid, blk, 0, stream>>>(Wp, WpT, 1024, 1024);
    transpose_convert_k<<<tgrid, blk, 0, stream>>>(Wo, WoT, 1024, 1024);
    bias_concat_k<<<dim3(12), blk, 0, stream>>>(bq, bk, bv, biascat);

    conv_bf16_k<<<dim3(8192), blk, 0, stream>>>(pos, S1);
    gemm7_k<0, 1><<<dim3(4, 128), dim3(512), 0, stream>>>(S1, WpT, nullptr, S2, 1024);

    conv_bf16_k<<<dim3(8192), blk, 0, stream>>>(inputs, S1);
    gemm7_k<1, 1><<<dim3(12, 128), dim3(512), 0, stream>>>(S1, WqT, biascat, S3, 3072);

    attn2_k<<<dim3(4096), blk, 0, stream>>>(S3, S2, ub, vb, masks, S1);

    gemm7_k<1, 0><<<dim3(4, 128), dim3(512), 0, stream>>>(S1, WoT, bo, (float*)d_out, 1024);
}

// Round 10
// 274.655 us; speedup vs baseline: 1.2386x; 1.0424x over previous
//
#include <hip/hip_runtime.h>

// RelativeMultiHeadAttention (B=8, T=2048, D_MODEL=1024, H=16, D_HEAD=64)
// Round 10: revert to R8's PROVEN GEMM (full-unroll, 3-region LDS, counted
// VMC(3), lgkm-before-barrier); keep only R9's safe piece (fused 5-way
// weight transpose). Attention: MFMA-based (R7).
// rel_shift: shifted[m]=pos_score[f=m+8 flat (b*(T+1)+t)]:
//   b_s=f/2049, t_s=f%2049; zero if t_s==0 else (b_s,t_s-1).

typedef __attribute__((ext_vector_type(8))) short short8;
typedef __attribute__((ext_vector_type(4))) float f32x4;

__device__ __forceinline__ ushort f2bf(float f) {
    unsigned u = __float_as_uint(f);
    u += 0x7FFFu + ((u >> 16) & 1u);   // round-to-nearest-even
    return (ushort)(u >> 16);
}
__device__ __forceinline__ float bf2f(ushort u) {
    return __uint_as_float(((unsigned)u) << 16);
}

typedef const unsigned int __attribute__((address_space(1)))* gas_t;
typedef unsigned int __attribute__((address_space(3)))* las_t;
__device__ __forceinline__ void gl_lds16(const ushort* g, ushort* l) {
    __builtin_amdgcn_global_load_lds((gas_t)g, (las_t)l, 16, 0, 0);
}

// ---------------- f32 -> bf16 convert (8 elems/thread) ----------------
__global__ __launch_bounds__(256)
void conv_bf16_k(const float* __restrict__ in, ushort* __restrict__ out)
{
    const size_t i = ((size_t)blockIdx.x * 256 + threadIdx.x) * 8;
    float4 a = *(const float4*)(in + i);
    float4 b = *(const float4*)(in + i + 4);
    short8 o = {(short)f2bf(a.x), (short)f2bf(a.y), (short)f2bf(a.z), (short)f2bf(a.w),
                (short)f2bf(b.x), (short)f2bf(b.y), (short)f2bf(b.z), (short)f2bf(b.w)};
    *(short8*)(out + i) = o;
}

// ---------------- fused 5x Wt[n][k] = bf16(W[k][n]) ----------------
__global__ __launch_bounds__(256)
void transpose5_k(const float* __restrict__ W0, const float* __restrict__ W1,
                  const float* __restrict__ W2, const float* __restrict__ W3,
                  const float* __restrict__ W4, ushort* __restrict__ Wt)
{
    __shared__ float tile[32][33];
    const int z = blockIdx.z;
    const float* W = (z == 0) ? W0 : (z == 1) ? W1 : (z == 2) ? W2 : (z == 3) ? W3 : W4;
    ushort* dst = Wt + (size_t)z * 1024 * 1024;
    const int tx = threadIdx.x & 31;
    const int ty = threadIdx.x >> 5;   // 0..7
    const int n0 = blockIdx.x * 32;
    const int k0 = blockIdx.y * 32;
#pragma unroll
    for (int i = 0; i < 4; ++i)
        tile[ty + i * 8][tx] = W[(size_t)(k0 + ty + i * 8) * 1024 + n0 + tx];
    __syncthreads();
#pragma unroll
    for (int i = 0; i < 4; ++i)
        dst[(size_t)(n0 + ty + i * 8) * 1024 + k0 + tx] = f2bf(tile[tx][ty + i * 8]);
}

// ---------------- bias concat [bq;bk;bv] ----------------
__global__ __launch_bounds__(256)
void bias_concat_k(const float* __restrict__ b0, const float* __restrict__ b1,
                   const float* __restrict__ b2, float* __restrict__ out)
{
    const int i = blockIdx.x * 256 + threadIdx.x;   // 0..3071
    const int s = i >> 10;
    const int j = i & 1023;
    out[i] = (s == 0) ? b0[j] : (s == 1) ? b1[j] : b2[j];
}

// ======== 128x256 GEMM, K=1024 hardcoded (NT=32), 3-region LDS (R8) ========
// 512 thr = 8 waves (2x4); per-wave C: 64x64 (4x4 frags), acc 64 AGPR.
// LDS: A [3][128][32]=24KB + B [3][256][32]=48KB = 72KB -> 2 blocks/CU.
// Swizzle: colbyte ^= ((row>>1)&3)<<4 (staging-source AND ds_read side).
// Body t: STAGE(t+2); ds_read A4+B4; VMC(3) [lands t+1]; lgkmcnt(0) [reads
//   done before barrier -> next overwrite safe]; s_barrier; sched_barrier;
//   16 MFMA. Tail: VMC(0)@t=30.

#define VMC(n) asm volatile("s_waitcnt vmcnt(" #n ")" ::: "memory")
#define KDIM 1024

template<int HAS_BIAS, int OUT_BF16>
__global__ __launch_bounds__(512, 4)
void gemm7_k(const ushort* __restrict__ A, const ushort* __restrict__ Bt,
             const float* __restrict__ bias, void* __restrict__ Cv,
             int N)
{
    __shared__ ushort As[3 * 4096];   // 24KB: [3][128][32]
    __shared__ ushort Bs[3 * 8192];   // 48KB: [3][256][32]
    const int tid = threadIdx.x;
    const int l = tid & 63;
    const int w = tid >> 6;
    const int wr = w >> 2;             // 0..1 (m 64-half)
    const int wc = w & 3;              // 0..3 (n 64-quarter)

    // XCD/L2-aware bijective remap (gx%4==0, gy%8==0)
    const int gx = gridDim.x;
    const int lin = blockIdx.y * gx + blockIdx.x;
    const int xcd = lin & 7;
    const int idx = lin >> 3;
    const int hb = gridDim.y >> 3;
    const int sxc = gx >> 2;
    const int g4 = idx >> 4;
    const int li = idx & 15;
    const int bx = (g4 % sxc) * 4 + (li & 3);
    const int by = xcd * hb + (g4 / sxc) * 4 + (li >> 2);
    const int bm = by * 128;
    const int bn = bx * 256;

    const int srow = tid >> 2;
    const int scol = ((tid & 3) ^ ((tid >> 3) & 3)) * 8;
    const ushort* Ag  = A  + (size_t)(bm + srow) * KDIM + scol;
    const ushort* Bg  = Bt + (size_t)(bn + srow) * KDIM + scol;
    const ushort* Bg2 = Bg + (size_t)128 * KDIM;
    const int lw = w * 512;

    const int lr = l & 15;
    const int fb = (((l >> 4) ^ ((l >> 1) & 3)) * 8);
    const int laneA = (wr * 64 + lr) * 32 + fb;
    const int laneB = (wc * 64 + lr) * 32 + fb;

    f32x4 acc[4][4];
#pragma unroll
    for (int i = 0; i < 4; ++i)
#pragma unroll
        for (int n = 0; n < 4; ++n)
            acc[i][n] = (f32x4){0.f, 0.f, 0.f, 0.f};

#define STAGE7(tt, rg) do { \
    ushort* ha = As + (rg) * 4096 + lw; \
    ushort* hbp = Bs + (rg) * 8192 + lw; \
    const size_t ko = (size_t)(tt) * 32; \
    gl_lds16(Ag + ko, ha); \
    gl_lds16(Bg + ko, hbp); \
    gl_lds16(Bg2 + ko, hbp + 4096); \
} while (0)

    // prologue: stage t0->r0, t1->r1; land t0; barrier
    STAGE7(0, 0);
    STAGE7(1, 1);
    VMC(3);
    __builtin_amdgcn_s_barrier();
    __builtin_amdgcn_sched_barrier(0);

#pragma unroll
    for (int t = 0; t < 32; ++t) {
        const int cur = t % 3;
        const int stg = (t + 2) % 3;
        if (t + 2 < 32) STAGE7(t + 2, stg);
        const ushort* ap = As + cur * 4096 + laneA;
        const ushort* bp = Bs + cur * 8192 + laneB;
        short8 af[4], bf4[4];
#pragma unroll
        for (int m = 0; m < 4; ++m) af[m] = *(const short8*)(ap + m * 512);
#pragma unroll
        for (int n = 0; n < 4; ++n) bf4[n] = *(const short8*)(bp + n * 512);
        if (t < 30) { VMC(3); }
        else if (t == 30) { VMC(0); }
        asm volatile("s_waitcnt lgkmcnt(0)" ::: "memory");
        __builtin_amdgcn_s_barrier();
        __builtin_amdgcn_sched_barrier(0);
#pragma unroll
        for (int m = 0; m < 4; ++m)
#pragma unroll
            for (int n = 0; n < 4; ++n)
                acc[m][n] = __builtin_amdgcn_mfma_f32_16x16x32_bf16(af[m], bf4[n], acc[m][n], 0, 0, 0);
    }
#undef STAGE7

    // epilogue: C/D layout col=lane&15, row=(lane>>4)*4+reg
    const int cr = (l >> 4) * 4;
    const int cc = l & 15;
    float bv[4];
#pragma unroll
    for (int n = 0; n < 4; ++n)
        bv[n] = HAS_BIAS ? bias[bn + wc * 64 + n * 16 + cc] : 0.f;
#pragma unroll
    for (int m = 0; m < 4; ++m) {
#pragma unroll
        for (int n = 0; n < 4; ++n) {
            const int col = bn + wc * 64 + n * 16 + cc;
#pragma unroll
            for (int r = 0; r < 4; ++r) {
                const int row = bm + wr * 64 + m * 16 + cr + r;
                float v = acc[m][n][r] + bv[n];
                if (OUT_BF16) ((ushort*)Cv)[(size_t)row * N + col] = f2bf(v);
                else          ((float*)Cv)[(size_t)row * N + col] = v;
            }
        }
    }
}

// ---------------- MFMA attention: 1 wave = 1 timestep (R7) ----------------
__global__ __launch_bounds__(256)
void attn2_k(const ushort* __restrict__ qkv, const ushort* __restrict__ pbuf,
             const float* __restrict__ ubias, const float* __restrict__ vbias,
             const int* __restrict__ masks, ushort* __restrict__ ctx)
{
    __shared__ __align__(16) float Pl[4][16 * 20];   // per-wave P tile, stride 20

    const int tid = threadIdx.x;
    const int w = tid >> 6;
    const int l = tid & 63;
    const int m = blockIdx.x * 4 + w;
    const int b2 = m >> 11;
    const int t2 = m & 2047;
    const int f  = m + 8;
    const int bs = f / 2049;
    const int ts = f - bs * 2049;
    const bool haspos = (ts != 0);
    const int mp = bs * 2048 + ts - 1;

    const int lr = l & 15;
    const int g  = l >> 4;
    const int ko = g * 8;

    const ushort* qb = qkv + (size_t)m * 3072;

    short8 quf[2], kf[2], qvf[2], pf[2];
#pragma unroll
    for (int c = 0; c < 2; ++c) {
        const int off = lr * 64 + c * 32 + ko;
        short8 q = *(const short8*)(qb + off);
        kf[c]    = *(const short8*)(qb + 1024 + off);
        float4 u0 = *(const float4*)(ubias + off);
        float4 u1 = *(const float4*)(ubias + off + 4);
        quf[c] = (short8){
            (short)f2bf(bf2f((ushort)q[0]) + u0.x), (short)f2bf(bf2f((ushort)q[1]) + u0.y),
            (short)f2bf(bf2f((ushort)q[2]) + u0.z), (short)f2bf(bf2f((ushort)q[3]) + u0.w),
            (short)f2bf(bf2f((ushort)q[4]) + u1.x), (short)f2bf(bf2f((ushort)q[5]) + u1.y),
            (short)f2bf(bf2f((ushort)q[6]) + u1.z), (short)f2bf(bf2f((ushort)q[7]) + u1.w)};
    }
    if (haspos) {
        const ushort* qmp = qkv + (size_t)mp * 3072;
        const ushort* pp  = pbuf + (size_t)mp * 1024;
#pragma unroll
        for (int c = 0; c < 2; ++c) {
            const int off = lr * 64 + c * 32 + ko;
            short8 q = *(const short8*)(qmp + off);
            pf[c]    = *(const short8*)(pp + off);
            float4 v0 = *(const float4*)(vbias + off);
            float4 v1 = *(const float4*)(vbias + off + 4);
            qvf[c] = (short8){
                (short)f2bf(bf2f((ushort)q[0]) + v0.x), (short)f2bf(bf2f((ushort)q[1]) + v0.y),
                (short)f2bf(bf2f((ushort)q[2]) + v0.z), (short)f2bf(bf2f((ushort)q[3]) + v0.w),
                (short)f2bf(bf2f((ushort)q[4]) + v1.x), (short)f2bf(bf2f((ushort)q[5]) + v1.y),
                (short)f2bf(bf2f((ushort)q[6]) + v1.z), (short)f2bf(bf2f((ushort)q[7]) + v1.w)};
        }
    }

    f32x4 s = (f32x4){0.f, 0.f, 0.f, 0.f};
    s = __builtin_amdgcn_mfma_f32_16x16x32_bf16(quf[0], kf[0], s, 0, 0, 0);
    s = __builtin_amdgcn_mfma_f32_16x16x32_bf16(quf[1], kf[1], s, 0, 0, 0);
    if (haspos) {
        s = __builtin_amdgcn_mfma_f32_16x16x32_bf16(qvf[0], pf[0], s, 0, 0, 0);
        s = __builtin_amdgcn_mfma_f32_16x16x32_bf16(qvf[1], pf[1], s, 0, 0, 0);
    }

    const bool mk = (masks[m] != 0);
    float sc[4];
#pragma unroll
    for (int r = 0; r < 4; ++r)
        sc[r] = mk ? s[r] * 0.03125f : 1e-9f;

    float mx[4], ex[4], sm[4];
#pragma unroll
    for (int r = 0; r < 4; ++r) {
        mx[r] = sc[r];
#pragma unroll
        for (int o = 8; o; o >>= 1) mx[r] = fmaxf(mx[r], __shfl_xor(mx[r], o, 64));
        ex[r] = __expf(sc[r] - mx[r]);
        sm[r] = ex[r];
#pragma unroll
        for (int o = 8; o; o >>= 1) sm[r] += __shfl_xor(sm[r], o, 64);
    }

    float* pw = Pl[w];
#pragma unroll
    for (int r = 0; r < 4; ++r)
        pw[(g * 4 + r) * 20 + lr] = ex[r] / sm[r];

    short8 pa;
    if (g < 2) {
        float4 p0 = *(const float4*)(pw + lr * 20 + g * 8);
        float4 p1 = *(const float4*)(pw + lr * 20 + g * 8 + 4);
        pa = (short8){(short)f2bf(p0.x), (short)f2bf(p0.y), (short)f2bf(p0.z), (short)f2bf(p0.w),
                      (short)f2bf(p1.x), (short)f2bf(p1.y), (short)f2bf(p1.z), (short)f2bf(p1.w)};
    } else {
        pa = (short8){0, 0, 0, 0, 0, 0, 0, 0};
    }

    const ushort* vb0 = qb + 2048;
    const size_t orow_base = (size_t)b2 * 2048 + (t2 >> 4);
    const int ocol_base = (t2 & 15) * 64;
#pragma unroll
    for (int n = 0; n < 4; ++n) {
        const int d0 = n * 16;
        short8 vf;
        if (g < 2) {
#pragma unroll
            for (int j = 0; j < 8; ++j)
                vf[j] = (short)vb0[(ko + j) * 64 + d0 + lr];
        } else {
            vf = (short8){0, 0, 0, 0, 0, 0, 0, 0};
        }
        f32x4 o = (f32x4){0.f, 0.f, 0.f, 0.f};
        o = __builtin_amdgcn_mfma_f32_16x16x32_bf16(pa, vf, o, 0, 0, 0);
#pragma unroll
        for (int r = 0; r < 4; ++r) {
            const int h1 = g * 4 + r;
            ctx[(orow_base + (size_t)h1 * 128) * 1024 + ocol_base + d0 + lr] = f2bf(o[r]);
        }
    }
}

extern "C" void kernel_launch(void* const* d_in, const int* in_sizes, int n_in,
                              void* d_out, int out_size, void* d_ws, size_t ws_size,
                              hipStream_t stream)
{
    (void)in_sizes; (void)n_in; (void)out_size; (void)ws_size;
    const float* inputs = (const float*)d_in[0];
    const float* pos    = (const float*)d_in[1];
    const int*   masks  = (const int*)d_in[2];
    const float* Wq = (const float*)d_in[3];
    const float* bq = (const float*)d_in[4];
    const float* Wk = (const float*)d_in[5];
    const float* bk = (const float*)d_in[6];
    const float* Wv = (const float*)d_in[7];
    const float* bv = (const float*)d_in[8];
    const float* Wp = (const float*)d_in[9];
    const float* Wo = (const float*)d_in[10];
    const float* bo = (const float*)d_in[11];
    const float* ub = (const float*)d_in[12];
    const float* vb = (const float*)d_in[13];

    // ws layout:
    //   [0,10MB)      WqT|WkT|WvT|WpT|WoT  (bf16 [N][K], contiguous)
    //   [10MB,+64KB)  biascat (f32[3072])
    //   S1 (32MB): pos_bf16 -> inputs_bf16 -> ctx
    //   S2 (32MB): pbuf  (pos @ Wp, bf16)
    //   S3 (96MB): qkv   ([16384][3072] bf16)
    char* ws = (char*)d_ws;
    const size_t WT_SZ = (size_t)1024 * 1024 * 2;
    ushort* WT  = (ushort*)(ws);                 // 5 consecutive transposed weights
    ushort* WqT = WT;
    ushort* WpT = (ushort*)(ws + 3 * WT_SZ);
    ushort* WoT = (ushort*)(ws + 4 * WT_SZ);
    float*  biascat = (float*)(ws + 5 * WT_SZ);
    char* bufs = ws + 5 * WT_SZ + 65536;
    const size_t S_SZ = (size_t)16384 * 1024 * 2;       // 32MB
    ushort* S1 = (ushort*)(bufs);
    ushort* S2 = (ushort*)(bufs + S_SZ);
    ushort* S3 = (ushort*)(bufs + 2 * S_SZ);            // 96MB

    dim3 blk(256);

    // fused weight transposes (z=0..4 -> Wq,Wk,Wv,Wp,Wo) + biases
    transpose5_k<<<dim3(32, 32, 5), blk, 0, stream>>>(Wq, Wk, Wv, Wp, Wo, WT);
    bias_concat_k<<<dim3(12), blk, 0, stream>>>(bq, bk, bv, biascat);

    conv_bf16_k<<<dim3(8192), blk, 0, stream>>>(pos, S1);
    gemm7_k<0, 1><<<dim3(4, 128), dim3(512), 0, stream>>>(S1, WpT, nullptr, S2, 1024);

    conv_bf16_k<<<dim3(8192), blk, 0, stream>>>(inputs, S1);
    gemm7_k<1, 1><<<dim3(12, 128), dim3(512), 0, stream>>>(S1, WqT, biascat, S3, 3072);

    attn2_k<<<dim3(4096), blk, 0, stream>>>(S3, S2, ub, vb, masks, S1);

    gemm7_k<1, 0><<<dim3(4, 128), dim3(512), 0, stream>>>(S1, WoT, bo, (float*)d_out, 1024);
}

// Round 11
// 274.421 us; speedup vs baseline: 1.2396x; 1.0009x over previous
//
#include <hip/hip_runtime.h>

// RelativeMultiHeadAttention (B=8, T=2048, D_MODEL=1024, H=16, D_HEAD=64)
// Round 11: R9's register-pipelined GEMM at __launch_bounds__(512,2) --
// 256-reg budget, no spills, valid VMC counting (R9's NaN = spill-VMEM
// corrupting vmcnt under the (512,4) 128-reg cap). 1 block/CU, in-wave
// MFMA(t-1) overlaps ds_read(t)+STAGE. Attention: MFMA-based (R7).
// rel_shift: shifted[m]=pos_score[f=m+8 flat (b*(T+1)+t)]:
//   b_s=f/2049, t_s=f%2049; zero if t_s==0 else (b_s,t_s-1).

typedef __attribute__((ext_vector_type(8))) short short8;
typedef __attribute__((ext_vector_type(4))) float f32x4;

__device__ __forceinline__ ushort f2bf(float f) {
    unsigned u = __float_as_uint(f);
    u += 0x7FFFu + ((u >> 16) & 1u);   // round-to-nearest-even
    return (ushort)(u >> 16);
}
__device__ __forceinline__ float bf2f(ushort u) {
    return __uint_as_float(((unsigned)u) << 16);
}

typedef const unsigned int __attribute__((address_space(1)))* gas_t;
typedef unsigned int __attribute__((address_space(3)))* las_t;
__device__ __forceinline__ void gl_lds16(const ushort* g, ushort* l) {
    __builtin_amdgcn_global_load_lds((gas_t)g, (las_t)l, 16, 0, 0);
}

// ---------------- f32 -> bf16 convert (8 elems/thread) ----------------
__global__ __launch_bounds__(256)
void conv_bf16_k(const float* __restrict__ in, ushort* __restrict__ out)
{
    const size_t i = ((size_t)blockIdx.x * 256 + threadIdx.x) * 8;
    float4 a = *(const float4*)(in + i);
    float4 b = *(const float4*)(in + i + 4);
    short8 o = {(short)f2bf(a.x), (short)f2bf(a.y), (short)f2bf(a.z), (short)f2bf(a.w),
                (short)f2bf(b.x), (short)f2bf(b.y), (short)f2bf(b.z), (short)f2bf(b.w)};
    *(short8*)(out + i) = o;
}

// ---------------- fused 5x Wt[n][k] = bf16(W[k][n]) ----------------
__global__ __launch_bounds__(256)
void transpose5_k(const float* __restrict__ W0, const float* __restrict__ W1,
                  const float* __restrict__ W2, const float* __restrict__ W3,
                  const float* __restrict__ W4, ushort* __restrict__ Wt)
{
    __shared__ float tile[32][33];
    const int z = blockIdx.z;
    const float* W = (z == 0) ? W0 : (z == 1) ? W1 : (z == 2) ? W2 : (z == 3) ? W3 : W4;
    ushort* dst = Wt + (size_t)z * 1024 * 1024;
    const int tx = threadIdx.x & 31;
    const int ty = threadIdx.x >> 5;   // 0..7
    const int n0 = blockIdx.x * 32;
    const int k0 = blockIdx.y * 32;
#pragma unroll
    for (int i = 0; i < 4; ++i)
        tile[ty + i * 8][tx] = W[(size_t)(k0 + ty + i * 8) * 1024 + n0 + tx];
    __syncthreads();
#pragma unroll
    for (int i = 0; i < 4; ++i)
        dst[(size_t)(n0 + ty + i * 8) * 1024 + k0 + tx] = f2bf(tile[tx][ty + i * 8]);
}

// ---------------- bias concat [bq;bk;bv] ----------------
__global__ __launch_bounds__(256)
void bias_concat_k(const float* __restrict__ b0, const float* __restrict__ b1,
                   const float* __restrict__ b2, float* __restrict__ out)
{
    const int i = blockIdx.x * 256 + threadIdx.x;   // 0..3071
    const int s = i >> 10;
    const int j = i & 1023;
    out[i] = (s == 0) ? b0[j] : (s == 1) ? b1[j] : b2[j];
}

// ======== 128x256 GEMM, K=1024 (NT=32), 3-region LDS, reg-pipelined ========
// 512 thr = 8 waves (2x4); per-wave C: 64x64 (4x4 frags), acc 64 AGPR.
// __launch_bounds__(512,2): 256-reg budget -> frag double-buffer (64 VGPR)
// fits WITHOUT spills -> VMC FIFO counting valid. 1 block/CU, 2 waves/SIMD.
// LDS: A [3][128][32]=24KB + B [3][256][32]=48KB = 72KB.
// Swizzle: colbyte ^= ((row>>1)&3)<<4 (staging-source AND ds_read side).
// Body t: STAGE(t+2); ds_read(t)->frag[t&1]; MFMA(t-1)<-frag[(t-1)&1]
//   (reg-only, overlaps in-flight reads); VMC(3) [forces t+1]; lgkmcnt(0)
//   [frag(t) landed + region safety pre-barrier]; s_barrier; sched_barrier.
// Tail: VMC(0)@t=30; final MFMA(31) after loop.

#define VMC(n) asm volatile("s_waitcnt vmcnt(" #n ")" ::: "memory")
#define KDIM 1024

template<int HAS_BIAS, int OUT_BF16>
__global__ __launch_bounds__(512, 2)
void gemm9_k(const ushort* __restrict__ A, const ushort* __restrict__ Bt,
             const float* __restrict__ bias, void* __restrict__ Cv,
             int N)
{
    __shared__ ushort As[3 * 4096];   // 24KB: [3][128][32]
    __shared__ ushort Bs[3 * 8192];   // 48KB: [3][256][32]
    const int tid = threadIdx.x;
    const int l = tid & 63;
    const int w = tid >> 6;
    const int wr = w >> 2;             // 0..1 (m 64-half)
    const int wc = w & 3;              // 0..3 (n 64-quarter)

    // XCD/L2-aware bijective remap (gx%4==0, gy%8==0)
    const int gx = gridDim.x;
    const int lin = blockIdx.y * gx + blockIdx.x;
    const int xcd = lin & 7;
    const int idx = lin >> 3;
    const int hb = gridDim.y >> 3;
    const int sxc = gx >> 2;
    const int g4 = idx >> 4;
    const int li = idx & 15;
    const int bx = (g4 % sxc) * 4 + (li & 3);
    const int by = xcd * hb + (g4 / sxc) * 4 + (li >> 2);
    const int bm = by * 128;
    const int bn = bx * 256;

    const int srow = tid >> 2;
    const int scol = ((tid & 3) ^ ((tid >> 3) & 3)) * 8;
    const ushort* Ag  = A  + (size_t)(bm + srow) * KDIM + scol;
    const ushort* Bg  = Bt + (size_t)(bn + srow) * KDIM + scol;
    const ushort* Bg2 = Bg + (size_t)128 * KDIM;
    const int lw = w * 512;

    const int lr = l & 15;
    const int fb = (((l >> 4) ^ ((l >> 1) & 3)) * 8);
    const int laneA = (wr * 64 + lr) * 32 + fb;
    const int laneB = (wc * 64 + lr) * 32 + fb;

    f32x4 acc[4][4];
#pragma unroll
    for (int i = 0; i < 4; ++i)
#pragma unroll
        for (int n = 0; n < 4; ++n)
            acc[i][n] = (f32x4){0.f, 0.f, 0.f, 0.f};

    short8 fa[2][4], fbv[2][4];   // parity-indexed frag double-buffer (static idx)

#define STAGE9(tt, rg) do { \
    ushort* ha = As + (rg) * 4096 + lw; \
    ushort* hbp = Bs + (rg) * 8192 + lw; \
    const size_t ko = (size_t)(tt) * 32; \
    gl_lds16(Ag + ko, ha); \
    gl_lds16(Bg + ko, hbp); \
    gl_lds16(Bg2 + ko, hbp + 4096); \
} while (0)

    // prologue: stage t0->r0, t1->r1; land t0; barrier
    STAGE9(0, 0);
    STAGE9(1, 1);
    VMC(3);
    __builtin_amdgcn_s_barrier();
    __builtin_amdgcn_sched_barrier(0);

#pragma unroll
    for (int t = 0; t < 32; ++t) {
        const int cur = t % 3;
        const int stg = (t + 2) % 3;
        const int pb = t & 1;          // frag buffer for tile t (static)
        if (t + 2 < 32) STAGE9(t + 2, stg);
        const ushort* ap = As + cur * 4096 + laneA;
        const ushort* bp = Bs + cur * 8192 + laneB;
#pragma unroll
        for (int m = 0; m < 4; ++m) fa[pb][m] = *(const short8*)(ap + m * 512);
#pragma unroll
        for (int n = 0; n < 4; ++n) fbv[pb][n] = *(const short8*)(bp + n * 512);
        if (t > 0) {
            const int qb2 = (t - 1) & 1;
#pragma unroll
            for (int m = 0; m < 4; ++m)
#pragma unroll
                for (int n = 0; n < 4; ++n)
                    acc[m][n] = __builtin_amdgcn_mfma_f32_16x16x32_bf16(fa[qb2][m], fbv[qb2][n], acc[m][n], 0, 0, 0);
        }
        if (t < 30) { VMC(3); }
        else if (t == 30) { VMC(0); }
        asm volatile("s_waitcnt lgkmcnt(0)" ::: "memory");
        __builtin_amdgcn_s_barrier();
        __builtin_amdgcn_sched_barrier(0);
    }
    // final tile 31 MFMA (frag buffer 31&1 = 1)
#pragma unroll
    for (int m = 0; m < 4; ++m)
#pragma unroll
        for (int n = 0; n < 4; ++n)
            acc[m][n] = __builtin_amdgcn_mfma_f32_16x16x32_bf16(fa[1][m], fbv[1][n], acc[m][n], 0, 0, 0);
#undef STAGE9

    // epilogue: C/D layout col=lane&15, row=(lane>>4)*4+reg
    const int cr = (l >> 4) * 4;
    const int cc = l & 15;
    float bv[4];
#pragma unroll
    for (int n = 0; n < 4; ++n)
        bv[n] = HAS_BIAS ? bias[bn + wc * 64 + n * 16 + cc] : 0.f;
#pragma unroll
    for (int m = 0; m < 4; ++m) {
#pragma unroll
        for (int n = 0; n < 4; ++n) {
            const int col = bn + wc * 64 + n * 16 + cc;
#pragma unroll
            for (int r = 0; r < 4; ++r) {
                const int row = bm + wr * 64 + m * 16 + cr + r;
                float v = acc[m][n][r] + bv[n];
                if (OUT_BF16) ((ushort*)Cv)[(size_t)row * N + col] = f2bf(v);
                else          ((float*)Cv)[(size_t)row * N + col] = v;
            }
        }
    }
}

// ---------------- MFMA attention: 1 wave = 1 timestep (R7) ----------------
__global__ __launch_bounds__(256)
void attn2_k(const ushort* __restrict__ qkv, const ushort* __restrict__ pbuf,
             const float* __restrict__ ubias, const float* __restrict__ vbias,
             const int* __restrict__ masks, ushort* __restrict__ ctx)
{
    __shared__ __align__(16) float Pl[4][16 * 20];   // per-wave P tile, stride 20

    const int tid = threadIdx.x;
    const int w = tid >> 6;
    const int l = tid & 63;
    const int m = blockIdx.x * 4 + w;
    const int b2 = m >> 11;
    const int t2 = m & 2047;
    const int f  = m + 8;
    const int bs = f / 2049;
    const int ts = f - bs * 2049;
    const bool haspos = (ts != 0);
    const int mp = bs * 2048 + ts - 1;

    const int lr = l & 15;
    const int g  = l >> 4;
    const int ko = g * 8;

    const ushort* qb = qkv + (size_t)m * 3072;

    short8 quf[2], kf[2], qvf[2], pf[2];
#pragma unroll
    for (int c = 0; c < 2; ++c) {
        const int off = lr * 64 + c * 32 + ko;
        short8 q = *(const short8*)(qb + off);
        kf[c]    = *(const short8*)(qb + 1024 + off);
        float4 u0 = *(const float4*)(ubias + off);
        float4 u1 = *(const float4*)(ubias + off + 4);
        quf[c] = (short8){
            (short)f2bf(bf2f((ushort)q[0]) + u0.x), (short)f2bf(bf2f((ushort)q[1]) + u0.y),
            (short)f2bf(bf2f((ushort)q[2]) + u0.z), (short)f2bf(bf2f((ushort)q[3]) + u0.w),
            (short)f2bf(bf2f((ushort)q[4]) + u1.x), (short)f2bf(bf2f((ushort)q[5]) + u1.y),
            (short)f2bf(bf2f((ushort)q[6]) + u1.z), (short)f2bf(bf2f((ushort)q[7]) + u1.w)};
    }
    if (haspos) {
        const ushort* qmp = qkv + (size_t)mp * 3072;
        const ushort* pp  = pbuf + (size_t)mp * 1024;
#pragma unroll
        for (int c = 0; c < 2; ++c) {
            const int off = lr * 64 + c * 32 + ko;
            short8 q = *(const short8*)(qmp + off);
            pf[c]    = *(const short8*)(pp + off);
            float4 v0 = *(const float4*)(vbias + off);
            float4 v1 = *(const float4*)(vbias + off + 4);
            qvf[c] = (short8){
                (short)f2bf(bf2f((ushort)q[0]) + v0.x), (short)f2bf(bf2f((ushort)q[1]) + v0.y),
                (short)f2bf(bf2f((ushort)q[2]) + v0.z), (short)f2bf(bf2f((ushort)q[3]) + v0.w),
                (short)f2bf(bf2f((ushort)q[4]) + v1.x), (short)f2bf(bf2f((ushort)q[5]) + v1.y),
                (short)f2bf(bf2f((ushort)q[6]) + v1.z), (short)f2bf(bf2f((ushort)q[7]) + v1.w)};
        }
    }

    f32x4 s = (f32x4){0.f, 0.f, 0.f, 0.f};
    s = __builtin_amdgcn_mfma_f32_16x16x32_bf16(quf[0], kf[0], s, 0, 0, 0);
    s = __builtin_amdgcn_mfma_f32_16x16x32_bf16(quf[1], kf[1], s, 0, 0, 0);
    if (haspos) {
        s = __builtin_amdgcn_mfma_f32_16x16x32_bf16(qvf[0], pf[0], s, 0, 0, 0);
        s = __builtin_amdgcn_mfma_f32_16x16x32_bf16(qvf[1], pf[1], s, 0, 0, 0);
    }

    const bool mk = (masks[m] != 0);
    float sc[4];
#pragma unroll
    for (int r = 0; r < 4; ++r)
        sc[r] = mk ? s[r] * 0.03125f : 1e-9f;

    float mx[4], ex[4], sm[4];
#pragma unroll
    for (int r = 0; r < 4; ++r) {
        mx[r] = sc[r];
#pragma unroll
        for (int o = 8; o; o >>= 1) mx[r] = fmaxf(mx[r], __shfl_xor(mx[r], o, 64));
        ex[r] = __expf(sc[r] - mx[r]);
        sm[r] = ex[r];
#pragma unroll
        for (int o = 8; o; o >>= 1) sm[r] += __shfl_xor(sm[r], o, 64);
    }

    float* pw = Pl[w];
#pragma unroll
    for (int r = 0; r < 4; ++r)
        pw[(g * 4 + r) * 20 + lr] = ex[r] / sm[r];

    short8 pa;
    if (g < 2) {
        float4 p0 = *(const float4*)(pw + lr * 20 + g * 8);
        float4 p1 = *(const float4*)(pw + lr * 20 + g * 8 + 4);
        pa = (short8){(short)f2bf(p0.x), (short)f2bf(p0.y), (short)f2bf(p0.z), (short)f2bf(p0.w),
                      (short)f2bf(p1.x), (short)f2bf(p1.y), (short)f2bf(p1.z), (short)f2bf(p1.w)};
    } else {
        pa = (short8){0, 0, 0, 0, 0, 0, 0, 0};
    }

    const ushort* vb0 = qb + 2048;
    const size_t orow_base = (size_t)b2 * 2048 + (t2 >> 4);
    const int ocol_base = (t2 & 15) * 64;
#pragma unroll
    for (int n = 0; n < 4; ++n) {
        const int d0 = n * 16;
        short8 vf;
        if (g < 2) {
#pragma unroll
            for (int j = 0; j < 8; ++j)
                vf[j] = (short)vb0[(ko + j) * 64 + d0 + lr];
        } else {
            vf = (short8){0, 0, 0, 0, 0, 0, 0, 0};
        }
        f32x4 o = (f32x4){0.f, 0.f, 0.f, 0.f};
        o = __builtin_amdgcn_mfma_f32_16x16x32_bf16(pa, vf, o, 0, 0, 0);
#pragma unroll
        for (int r = 0; r < 4; ++r) {
            const int h1 = g * 4 + r;
            ctx[(orow_base + (size_t)h1 * 128) * 1024 + ocol_base + d0 + lr] = f2bf(o[r]);
        }
    }
}

extern "C" void kernel_launch(void* const* d_in, const int* in_sizes, int n_in,
                              void* d_out, int out_size, void* d_ws, size_t ws_size,
                              hipStream_t stream)
{
    (void)in_sizes; (void)n_in; (void)out_size; (void)ws_size;
    const float* inputs = (const float*)d_in[0];
    const float* pos    = (const float*)d_in[1];
    const int*   masks  = (const int*)d_in[2];
    const float* Wq = (const float*)d_in[3];
    const float* bq = (const float*)d_in[4];
    const float* Wk = (const float*)d_in[5];
    const float* bk = (const float*)d_in[6];
    const float* Wv = (const float*)d_in[7];
    const float* bv = (const float*)d_in[8];
    const float* Wp = (const float*)d_in[9];
    const float* Wo = (const float*)d_in[10];
    const float* bo = (const float*)d_in[11];
    const float* ub = (const float*)d_in[12];
    const float* vb = (const float*)d_in[13];

    // ws layout:
    //   [0,10MB)      WqT|WkT|WvT|WpT|WoT  (bf16 [N][K], contiguous)
    //   [10MB,+64KB)  biascat (f32[3072])
    //   S1 (32MB): pos_bf16 -> inputs_bf16 -> ctx
    //   S2 (32MB): pbuf  (pos @ Wp, bf16)
    //   S3 (96MB): qkv   ([16384][3072] bf16)
    char* ws = (char*)d_ws;
    const size_t WT_SZ = (size_t)1024 * 1024 * 2;
    ushort* WT  = (ushort*)(ws);                 // 5 consecutive transposed weights
    ushort* WqT = WT;
    ushort* WpT = (ushort*)(ws + 3 * WT_SZ);
    ushort* WoT = (ushort*)(ws + 4 * WT_SZ);
    float*  biascat = (float*)(ws + 5 * WT_SZ);
    char* bufs = ws + 5 * WT_SZ + 65536;
    const size_t S_SZ = (size_t)16384 * 1024 * 2;       // 32MB
    ushort* S1 = (ushort*)(bufs);
    ushort* S2 = (ushort*)(bufs + S_SZ);
    ushort* S3 = (ushort*)(bufs + 2 * S_SZ);            // 96MB

    dim3 blk(256);

    // fused weight transposes (z=0..4 -> Wq,Wk,Wv,Wp,Wo) + biases
    transpose5_k<<<dim3(32, 32, 5), blk, 0, stream>>>(Wq, Wk, Wv, Wp, Wo, WT);
    bias_concat_k<<<dim3(12), blk, 0, stream>>>(bq, bk, bv, biascat);

    conv_bf16_k<<<dim3(8192), blk, 0, stream>>>(pos, S1);
    gemm9_k<0, 1><<<dim3(4, 128), dim3(512), 0, stream>>>(S1, WpT, nullptr, S2, 1024);

    conv_bf16_k<<<dim3(8192), blk, 0, stream>>>(inputs, S1);
    gemm9_k<1, 1><<<dim3(12, 128), dim3(512), 0, stream>>>(S1, WqT, biascat, S3, 3072);

    attn2_k<<<dim3(4096), blk, 0, stream>>>(S3, S2, ub, vb, masks, S1);

    gemm9_k<1, 0><<<dim3(4, 128), dim3(512), 0, stream>>>(S1, WoT, bo, (float*)d_out, 1024);
}